// Round 2
// baseline (822.730 us; speedup 1.0000x reference)
//
#include <hip/hip_runtime.h>
#include <math.h>

typedef __bf16 bf16;
typedef __bf16 bf16x8 __attribute__((ext_vector_type(8)));
typedef __bf16 bf16x4 __attribute__((ext_vector_type(4)));
typedef __bf16 bf16x2 __attribute__((ext_vector_type(2)));
typedef float f32x4 __attribute__((ext_vector_type(4)));

#define ROWS 16384   // B*T
#define DD   1024

// ---------------- 0. cast f32 -> bf16 (weights) ----------------
__global__ __launch_bounds__(256) void cast_kernel(
    const float* __restrict__ src, bf16* __restrict__ dst, int n)
{
  int i = (blockIdx.x * 256 + threadIdx.x) * 8;
  if (i >= n) return;
  float4 a = *(const float4*)(src + i);
  float4 b = *(const float4*)(src + i + 4);
  bf16x8 o;
  o[0] = (bf16)a.x; o[1] = (bf16)a.y; o[2] = (bf16)a.z; o[3] = (bf16)a.w;
  o[4] = (bf16)b.x; o[5] = (bf16)b.y; o[6] = (bf16)b.z; o[7] = (bf16)b.w;
  *(bf16x8*)(dst + i) = o;
}

// ---------------- 1. x = frame_features + sinusoidal PE (f32 in, bf16 out) ----
__global__ __launch_bounds__(256) void pe_add_kernel(
    const float* __restrict__ ff, const int* __restrict__ idx, bf16* __restrict__ x)
{
  int p   = blockIdx.x * 256 + threadIdx.x;   // over ROWS*512 sin/cos pairs
  int row = p >> 9;
  int j   = p & 511;
  float pos = (float)idx[row];
  float d2  = (float)(2 * j) * (1.0f / 1024.0f);
  float dv  = expf(-9.210340371976184f * d2);   // 10000^(-2j/D)
  float ang = pos * dv;
  float s, c;
  sincosf(ang, &s, &c);
  int base = row * 1024 + 2 * j;
  float2 f = *(const float2*)(ff + base);
  bf16x2 o;
  o[0] = (bf16)(f.x + s);
  o[1] = (bf16)(f.y + c);
  *(bf16x2*)(x + base) = o;
}

// ---------------- 2. GEMM: C[M,N] = A[M,K] * Bw[N,K]^T + bias (+resid) (gelu?) ----
// 128x128 tile, BK=32, 256 threads = 4 waves, each wave 64x64 (4x4 of 16x16x32 MFMA)
template<bool GELU, bool RES>
__global__ __launch_bounds__(256, 2) void gemm_bt(
    const bf16* __restrict__ A, const bf16* __restrict__ Bw,
    const float* __restrict__ bias, const bf16* __restrict__ resid,
    bf16* __restrict__ C, int M, int N, int K)
{
  __shared__ bf16 sA[128 * 40];   // +8 pad: 80B row stride -> conflict-free b128 reads
  __shared__ bf16 sB[128 * 40];

  const int tid  = threadIdx.x;
  const int bm   = blockIdx.y * 128;
  const int bn   = blockIdx.x * 128;

  const int wave = tid >> 6;
  const int lane = tid & 63;
  const int wr   = (wave >> 1) * 64;   // wave row offset in tile
  const int wc   = (wave & 1) * 64;    // wave col offset in tile
  const int ln   = lane & 15;
  const int q    = lane >> 4;

  const int sr = tid >> 2;            // staging row 0..63
  const int sc = (tid & 3) * 8;       // staging k-offset

  f32x4 acc[4][4];
#pragma unroll
  for (int i = 0; i < 4; i++)
#pragma unroll
    for (int jj = 0; jj < 4; jj++) acc[i][jj] = {0.f, 0.f, 0.f, 0.f};

  const bf16* pa0 = A  + (size_t)(bm + sr)      * K + sc;
  const bf16* pa1 = A  + (size_t)(bm + sr + 64) * K + sc;
  const bf16* pb0 = Bw + (size_t)(bn + sr)      * K + sc;
  const bf16* pb1 = Bw + (size_t)(bn + sr + 64) * K + sc;

  for (int k0 = 0; k0 < K; k0 += 32) {
    float4 a0 = *(const float4*)(pa0 + k0);
    float4 a1 = *(const float4*)(pa1 + k0);
    float4 b0 = *(const float4*)(pb0 + k0);
    float4 b1 = *(const float4*)(pb1 + k0);
    __syncthreads();   // previous iter's LDS reads done
    *(float4*)(&sA[sr * 40 + sc])        = a0;
    *(float4*)(&sA[(sr + 64) * 40 + sc]) = a1;
    *(float4*)(&sB[sr * 40 + sc])        = b0;
    *(float4*)(&sB[(sr + 64) * 40 + sc]) = b1;
    __syncthreads();

    bf16x8 af[4], bfr[4];
#pragma unroll
    for (int t = 0; t < 4; t++) {
      af[t]  = *(const bf16x8*)(&sA[(wr + t * 16 + ln) * 40 + q * 8]);
      bfr[t] = *(const bf16x8*)(&sB[(wc + t * 16 + ln) * 40 + q * 8]);
    }
#pragma unroll
    for (int tm = 0; tm < 4; tm++)
#pragma unroll
      for (int tn = 0; tn < 4; tn++)
        acc[tm][tn] = __builtin_amdgcn_mfma_f32_16x16x32_bf16(
            af[tm], bfr[tn], acc[tm][tn], 0, 0, 0);
  }

  // epilogue: C/D layout col=lane&15, row=(lane>>4)*4+reg
#pragma unroll
  for (int tm = 0; tm < 4; tm++) {
#pragma unroll
    for (int tn = 0; tn < 4; tn++) {
      int gn = bn + wc + tn * 16 + ln;
      float bv = bias[gn];
#pragma unroll
      for (int i = 0; i < 4; i++) {
        int gm = bm + wr + tm * 16 + q * 4 + i;
        size_t off = (size_t)gm * N + gn;
        float v = acc[tm][tn][i] + bv;
        if (RES) v += (float)resid[off];
        if (GELU) v = 0.5f * v * (1.0f + erff(v * 0.70710678118654752f));
        C[off] = (bf16)v;
      }
    }
  }
}

// ---------------- 3. windowed attention: one block per (window, head) ----------
__global__ __launch_bounds__(256) void attn_kernel(
    const bf16* __restrict__ qkv, bf16* __restrict__ o)
{
  __shared__ float sq[16][132], sk[16][132], sv[16][132];
  __shared__ float ss[16][17];

  int wid = blockIdx.x;
  int h   = wid & 7;
  int win = wid >> 3;
  int tb  = win * 16;     // token base row

  int t  = threadIdx.x;
  int r  = t >> 4;        // 0..15
  int c8 = (t & 15) * 8;  // 0..120

  const bf16* base = qkv + (size_t)(tb + r) * 3072 + c8;
  bf16x8 qv = *(const bf16x8*)(base + h * 128);
  bf16x8 kv = *(const bf16x8*)(base + 1024 + h * 128);
  bf16x8 vv = *(const bf16x8*)(base + 2048 + h * 128);
#pragma unroll
  for (int u = 0; u < 8; u++) {
    sq[r][c8 + u] = (float)qv[u];
    sk[r][c8 + u] = (float)kv[u];
    sv[r][c8 + u] = (float)vv[u];
  }
  __syncthreads();

  {  // scores: thread (i,j) does 128-dot
    int i = t >> 4, j = t & 15;
    float s = 0.f;
#pragma unroll 8
    for (int d = 0; d < 128; d++) s += sq[i][d] * sk[j][d];
    ss[i][j] = s * 0.08838834764831845f;   // 1/sqrt(128)
  }
  __syncthreads();

  if (t < 16) {  // softmax, one thread per row
    float m = -1e30f;
    for (int j = 0; j < 16; j++) m = fmaxf(m, ss[t][j]);
    float sum = 0.f;
    for (int j = 0; j < 16; j++) { float e = expf(ss[t][j] - m); ss[t][j] = e; sum += e; }
    float inv = 1.0f / sum;
    for (int j = 0; j < 16; j++) ss[t][j] *= inv;
  }
  __syncthreads();

  {  // o = attn @ v : thread does 8 output elems
    int i = t >> 4; int d0 = (t & 15) * 8;
    float acc[8] = {0, 0, 0, 0, 0, 0, 0, 0};
#pragma unroll
    for (int j = 0; j < 16; j++) {
      float a = ss[i][j];
#pragma unroll
      for (int u = 0; u < 8; u++) acc[u] += a * sv[j][d0 + u];
    }
    bf16* op = o + (size_t)(tb + i) * 1024 + h * 128 + d0;
#pragma unroll
    for (int u = 0; u < 8; u++) op[u] = (bf16)acc[u];
  }
}

// ---------------- 4. LayerNorm (row = 1024, biased var), templated output ------
template<typename OUT_T>
__global__ __launch_bounds__(256) void ln_kernel(
    const bf16* __restrict__ x, const float* __restrict__ g,
    const float* __restrict__ b, OUT_T* __restrict__ y)
{
  __shared__ float red[8];
  int row = blockIdx.x;
  int t   = threadIdx.x;
  int lane = t & 63, wave = t >> 6;

  bf16x4 v4 = *(const bf16x4*)(x + (size_t)row * 1024 + t * 4);
  float v[4];
  float s = 0.f, sq = 0.f;
#pragma unroll
  for (int u = 0; u < 4; u++) {
    v[u] = (float)v4[u];
    s += v[u];
    sq += v[u] * v[u];
  }
  for (int off = 32; off > 0; off >>= 1) {
    s  += __shfl_down(s, off);
    sq += __shfl_down(sq, off);
  }
  if (lane == 0) { red[wave * 2] = s; red[wave * 2 + 1] = sq; }
  __syncthreads();
  float st = red[0] + red[2] + red[4] + red[6];
  float qt = red[1] + red[3] + red[5] + red[7];
  float mean = st * (1.0f / 1024.0f);
  float var  = qt * (1.0f / 1024.0f) - mean * mean;
  float inv  = rsqrtf(var + 1e-5f);
  int c = t * 4;
  OUT_T* yr = y + (size_t)row * 1024 + c;
#pragma unroll
  for (int u = 0; u < 4; u++)
    yr[u] = (OUT_T)((v[u] - mean) * inv * g[c + u] + b[c + u]);
}

// ---------------- launch ----------------
extern "C" void kernel_launch(void* const* d_in, const int* in_sizes, int n_in,
                              void* d_out, int out_size, void* d_ws, size_t ws_size,
                              hipStream_t stream) {
  const float* ff    = (const float*)d_in[0];
  const int*   idx   = (const int*)d_in[1];
  const float* w_qkv = (const float*)d_in[2];
  const float* b_qkv = (const float*)d_in[3];
  const float* w_out = (const float*)d_in[4];
  const float* b_out = (const float*)d_in[5];
  const float* w1    = (const float*)d_in[6];
  const float* b1    = (const float*)d_in[7];
  const float* w2    = (const float*)d_in[8];
  const float* b2    = (const float*)d_in[9];
  const float* g1    = (const float*)d_in[10];
  const float* be1   = (const float*)d_in[11];
  const float* g2    = (const float*)d_in[12];
  const float* be2   = (const float*)d_in[13];
  float* out = (float*)d_out;

  char* p = (char*)d_ws;
  bf16* x_bf = (bf16*)p;  p += (size_t)ROWS * 1024 * 2;   // 32MB
  bf16* big  = (bf16*)p;  p += (size_t)ROWS * 4096 * 2;   // 128MB: qkv|o, later gelu acts
  bf16* s_bf = (bf16*)p;  p += (size_t)ROWS * 1024 * 2;   // 32MB
  bf16* h_bf = (bf16*)p;  p += (size_t)ROWS * 1024 * 2;   // 32MB
  bf16* wqb  = (bf16*)p;  p += (size_t)3072 * 1024 * 2;
  bf16* wob  = (bf16*)p;  p += (size_t)1024 * 1024 * 2;
  bf16* w1b  = (bf16*)p;  p += (size_t)4096 * 1024 * 2;
  bf16* w2b  = (bf16*)p;  p += (size_t)1024 * 4096 * 2;
  bf16* o_bf = big + (size_t)ROWS * 3072;   // lives in big's tail during attention
  bf16* g_bf = big;                          // reuses big after attention done

  cast_kernel<<<3072 * 1024 / 8 / 256, 256, 0, stream>>>(w_qkv, wqb, 3072 * 1024);
  cast_kernel<<<1024 * 1024 / 8 / 256, 256, 0, stream>>>(w_out, wob, 1024 * 1024);
  cast_kernel<<<4096 * 1024 / 8 / 256, 256, 0, stream>>>(w1, w1b, 4096 * 1024);
  cast_kernel<<<1024 * 4096 / 8 / 256, 256, 0, stream>>>(w2, w2b, 1024 * 4096);

  pe_add_kernel<<<ROWS * 512 / 256, 256, 0, stream>>>(ff, idx, x_bf);
  gemm_bt<false, false><<<dim3(3072 / 128, ROWS / 128), 256, 0, stream>>>(
      x_bf, wqb, b_qkv, nullptr, big, ROWS, 3072, 1024);
  attn_kernel<<<(ROWS / 16) * 8, 256, 0, stream>>>(big, o_bf);
  gemm_bt<false, true><<<dim3(1024 / 128, ROWS / 128), 256, 0, stream>>>(
      o_bf, wob, b_out, x_bf, s_bf, ROWS, 1024, 1024);
  ln_kernel<bf16><<<ROWS, 256, 0, stream>>>(s_bf, g1, be1, h_bf);
  gemm_bt<true, false><<<dim3(4096 / 128, ROWS / 128), 256, 0, stream>>>(
      h_bf, w1b, b1, nullptr, g_bf, ROWS, 4096, 1024);
  gemm_bt<false, true><<<dim3(1024 / 128, ROWS / 128), 256, 0, stream>>>(
      g_bf, w2b, b2, h_bf, s_bf, ROWS, 1024, 4096);
  ln_kernel<float><<<ROWS, 256, 0, stream>>>(s_bf, g2, be2, out);
}

// Round 3
// 755.656 us; speedup vs baseline: 1.0888x; 1.0888x over previous
//
#include <hip/hip_runtime.h>
#include <math.h>

typedef __bf16 bf16;
typedef __bf16 bf16x8 __attribute__((ext_vector_type(8)));
typedef __bf16 bf16x4 __attribute__((ext_vector_type(4)));
typedef __bf16 bf16x2 __attribute__((ext_vector_type(2)));
typedef float f32x4 __attribute__((ext_vector_type(4)));

#define ROWS 16384   // B*T
#define DD   1024

// ---- direct global->LDS 16B DMA (gfx950). LDS dest = wave-uniform base + lane*16.
typedef __attribute__((address_space(3))) void* lds_vp;
typedef const __attribute__((address_space(1))) void* glb_vp;
__device__ __forceinline__ void gload16(const void* g, void* l) {
  __builtin_amdgcn_global_load_lds((glb_vp)g, (lds_vp)l, 16, 0, 0);
}

// ---------------- 0. cast f32 -> bf16 (weights) ----------------
__global__ __launch_bounds__(256) void cast_kernel(
    const float* __restrict__ src, bf16* __restrict__ dst, int n)
{
  int i = (blockIdx.x * 256 + threadIdx.x) * 8;
  if (i >= n) return;
  float4 a = *(const float4*)(src + i);
  float4 b = *(const float4*)(src + i + 4);
  bf16x8 o;
  o[0] = (bf16)a.x; o[1] = (bf16)a.y; o[2] = (bf16)a.z; o[3] = (bf16)a.w;
  o[4] = (bf16)b.x; o[5] = (bf16)b.y; o[6] = (bf16)b.z; o[7] = (bf16)b.w;
  *(bf16x8*)(dst + i) = o;
}

// ---------------- 1. x = frame_features + sinusoidal PE (f32 in, bf16 out) ----
__global__ __launch_bounds__(256) void pe_add_kernel(
    const float* __restrict__ ff, const int* __restrict__ idx, bf16* __restrict__ x)
{
  int p   = blockIdx.x * 256 + threadIdx.x;   // over ROWS*512 sin/cos pairs
  int row = p >> 9;
  int j   = p & 511;
  float pos = (float)idx[row];
  float d2  = (float)(2 * j) * (1.0f / 1024.0f);
  float dv  = expf(-9.210340371976184f * d2);   // 10000^(-2j/D)
  float ang = pos * dv;
  float s, c;
  sincosf(ang, &s, &c);
  int base = row * 1024 + 2 * j;
  float2 f = *(const float2*)(ff + base);
  bf16x2 o;
  o[0] = (bf16)(f.x + s);
  o[1] = (bf16)(f.y + c);
  *(bf16x2*)(x + base) = o;
}

// ---------------- 2. GEMM: C[M,N] = A[M,K] * Bw[N,K]^T + bias (+resid) (gelu?) ----
// m97 structure: 128x128 tile, BK=32, global_load_lds(16B) staging, linear LDS.
// XCD swizzle: lid&7 -> XCD; XCD k owns M-stripe of 16 y-blocks, walks y fast.
// Requires gridDim.y == 128 (all calls here have M=16384).
template<bool GELU, bool RES>
__global__ __launch_bounds__(256, 2) void gemm_bt(
    const bf16* __restrict__ A, const bf16* __restrict__ Bw,
    const float* __restrict__ bias, const bf16* __restrict__ resid,
    bf16* __restrict__ C, int M, int N, int K)
{
  __shared__ bf16 sA[128 * 32];   // linear, no pad (global_load_lds constraint)
  __shared__ bf16 sB[128 * 32];

  const int tid = threadIdx.x;

  int lid = blockIdx.y * gridDim.x + blockIdx.x;
  int xcd = lid & 7;
  int j   = lid >> 3;
  const int bm = (xcd * 16 + (j & 15)) * 128;
  const int bn = (j >> 4) * 128;

  const int wave = tid >> 6;
  const int lane = tid & 63;
  const int wr   = (wave >> 1) * 64;   // wave row offset in tile
  const int wc   = (wave & 1) * 64;    // wave col offset in tile
  const int ln   = lane & 15;
  const int q    = lane >> 4;

  // staging: chunk c in {wave, wave+4}; chunk covers rows [c*16, c*16+16),
  // lane l -> row c*16 + (l>>2), k-granule (l&3)*8. LDS = chunk base + l*16B.
  const int srow = lane >> 2;
  const int sgr  = (lane & 3) * 8;

  f32x4 acc[4][4];
#pragma unroll
  for (int i = 0; i < 4; i++)
#pragma unroll
    for (int jj = 0; jj < 4; jj++) acc[i][jj] = {0.f, 0.f, 0.f, 0.f};

  const bf16* ga0 = A  + (size_t)(bm + wave * 16 + srow) * K + sgr;
  const bf16* ga1 = A  + (size_t)(bm + (wave + 4) * 16 + srow) * K + sgr;
  const bf16* gb0 = Bw + (size_t)(bn + wave * 16 + srow) * K + sgr;
  const bf16* gb1 = Bw + (size_t)(bn + (wave + 4) * 16 + srow) * K + sgr;
  bf16* la0 = &sA[(wave * 16) * 32];
  bf16* la1 = &sA[((wave + 4) * 16) * 32];
  bf16* lb0 = &sB[(wave * 16) * 32];
  bf16* lb1 = &sB[((wave + 4) * 16) * 32];

  for (int k0 = 0; k0 < K; k0 += 32) {
    __syncthreads();   // previous iter's LDS reads done
    gload16(ga0 + k0, la0);
    gload16(ga1 + k0, la1);
    gload16(gb0 + k0, lb0);
    gload16(gb1 + k0, lb1);
    __syncthreads();   // compiler inserts s_waitcnt vmcnt(0) before barrier

    bf16x8 af[4], bfr[4];
#pragma unroll
    for (int t = 0; t < 4; t++) {
      af[t]  = *(const bf16x8*)(&sA[(wr + t * 16 + ln) * 32 + q * 8]);
      bfr[t] = *(const bf16x8*)(&sB[(wc + t * 16 + ln) * 32 + q * 8]);
    }
#pragma unroll
    for (int tm = 0; tm < 4; tm++)
#pragma unroll
      for (int tn = 0; tn < 4; tn++)
        acc[tm][tn] = __builtin_amdgcn_mfma_f32_16x16x32_bf16(
            af[tm], bfr[tn], acc[tm][tn], 0, 0, 0);
  }

  // epilogue: C/D layout col=lane&15, row=(lane>>4)*4+reg
#pragma unroll
  for (int tm = 0; tm < 4; tm++) {
#pragma unroll
    for (int tn = 0; tn < 4; tn++) {
      int gn = bn + wc + tn * 16 + ln;
      float bv = bias[gn];
#pragma unroll
      for (int i = 0; i < 4; i++) {
        int gm = bm + wr + tm * 16 + q * 4 + i;
        size_t off = (size_t)gm * N + gn;
        float v = acc[tm][tn][i] + bv;
        if (RES) v += (float)resid[off];
        if (GELU) v = 0.5f * v * (1.0f + erff(v * 0.70710678118654752f));
        C[off] = (bf16)v;
      }
    }
  }
}

// ---------------- 3. windowed attention: one block per (window, head) ----------
__global__ __launch_bounds__(256) void attn_kernel(
    const bf16* __restrict__ qkv, bf16* __restrict__ o)
{
  __shared__ float sq[16][132], sk[16][132], sv[16][132];
  __shared__ float ss[16][17];

  int wid = blockIdx.x;
  int h   = wid & 7;
  int win = wid >> 3;
  int tb  = win * 16;     // token base row

  int t  = threadIdx.x;
  int r  = t >> 4;        // 0..15
  int c8 = (t & 15) * 8;  // 0..120

  const bf16* base = qkv + (size_t)(tb + r) * 3072 + c8;
  bf16x8 qv = *(const bf16x8*)(base + h * 128);
  bf16x8 kv = *(const bf16x8*)(base + 1024 + h * 128);
  bf16x8 vv = *(const bf16x8*)(base + 2048 + h * 128);
#pragma unroll
  for (int u = 0; u < 8; u++) {
    sq[r][c8 + u] = (float)qv[u];
    sk[r][c8 + u] = (float)kv[u];
    sv[r][c8 + u] = (float)vv[u];
  }
  __syncthreads();

  {  // scores: thread (i,j) does 128-dot
    int i = t >> 4, jj = t & 15;
    float s = 0.f;
#pragma unroll 8
    for (int d = 0; d < 128; d++) s += sq[i][d] * sk[jj][d];
    ss[i][jj] = s * 0.08838834764831845f;   // 1/sqrt(128)
  }
  __syncthreads();

  if (t < 16) {  // softmax, one thread per row
    float m = -1e30f;
    for (int jj = 0; jj < 16; jj++) m = fmaxf(m, ss[t][jj]);
    float sum = 0.f;
    for (int jj = 0; jj < 16; jj++) { float e = expf(ss[t][jj] - m); ss[t][jj] = e; sum += e; }
    float inv = 1.0f / sum;
    for (int jj = 0; jj < 16; jj++) ss[t][jj] *= inv;
  }
  __syncthreads();

  {  // o = attn @ v : thread does 8 output elems
    int i = t >> 4; int d0 = (t & 15) * 8;
    float acc[8] = {0, 0, 0, 0, 0, 0, 0, 0};
#pragma unroll
    for (int jj = 0; jj < 16; jj++) {
      float a = ss[i][jj];
#pragma unroll
      for (int u = 0; u < 8; u++) acc[u] += a * sv[jj][d0 + u];
    }
    bf16* op = o + (size_t)(tb + i) * 1024 + h * 128 + d0;
#pragma unroll
    for (int u = 0; u < 8; u++) op[u] = (bf16)acc[u];
  }
}

// ---------------- 4. LayerNorm (row = 1024, biased var), templated output ------
template<typename OUT_T>
__global__ __launch_bounds__(256) void ln_kernel(
    const bf16* __restrict__ x, const float* __restrict__ g,
    const float* __restrict__ b, OUT_T* __restrict__ y)
{
  __shared__ float red[8];
  int row = blockIdx.x;
  int t   = threadIdx.x;
  int lane = t & 63, wave = t >> 6;

  bf16x4 v4 = *(const bf16x4*)(x + (size_t)row * 1024 + t * 4);
  float v[4];
  float s = 0.f, sq = 0.f;
#pragma unroll
  for (int u = 0; u < 4; u++) {
    v[u] = (float)v4[u];
    s += v[u];
    sq += v[u] * v[u];
  }
  for (int off = 32; off > 0; off >>= 1) {
    s  += __shfl_down(s, off);
    sq += __shfl_down(sq, off);
  }
  if (lane == 0) { red[wave * 2] = s; red[wave * 2 + 1] = sq; }
  __syncthreads();
  float st = red[0] + red[2] + red[4] + red[6];
  float qt = red[1] + red[3] + red[5] + red[7];
  float mean = st * (1.0f / 1024.0f);
  float var  = qt * (1.0f / 1024.0f) - mean * mean;
  float inv  = rsqrtf(var + 1e-5f);
  int c = t * 4;
  OUT_T* yr = y + (size_t)row * 1024 + c;
#pragma unroll
  for (int u = 0; u < 4; u++)
    yr[u] = (OUT_T)((v[u] - mean) * inv * g[c + u] + b[c + u]);
}

// ---------------- launch ----------------
extern "C" void kernel_launch(void* const* d_in, const int* in_sizes, int n_in,
                              void* d_out, int out_size, void* d_ws, size_t ws_size,
                              hipStream_t stream) {
  const float* ff    = (const float*)d_in[0];
  const int*   idx   = (const int*)d_in[1];
  const float* w_qkv = (const float*)d_in[2];
  const float* b_qkv = (const float*)d_in[3];
  const float* w_out = (const float*)d_in[4];
  const float* b_out = (const float*)d_in[5];
  const float* w1    = (const float*)d_in[6];
  const float* b1    = (const float*)d_in[7];
  const float* w2    = (const float*)d_in[8];
  const float* b2    = (const float*)d_in[9];
  const float* g1    = (const float*)d_in[10];
  const float* be1   = (const float*)d_in[11];
  const float* g2    = (const float*)d_in[12];
  const float* be2   = (const float*)d_in[13];
  float* out = (float*)d_out;

  char* p = (char*)d_ws;
  bf16* x_bf = (bf16*)p;  p += (size_t)ROWS * 1024 * 2;   // 32MB
  bf16* big  = (bf16*)p;  p += (size_t)ROWS * 4096 * 2;   // 128MB: qkv|o, later gelu acts
  bf16* s_bf = (bf16*)p;  p += (size_t)ROWS * 1024 * 2;   // 32MB
  bf16* h_bf = (bf16*)p;  p += (size_t)ROWS * 1024 * 2;   // 32MB
  bf16* wqb  = (bf16*)p;  p += (size_t)3072 * 1024 * 2;
  bf16* wob  = (bf16*)p;  p += (size_t)1024 * 1024 * 2;
  bf16* w1b  = (bf16*)p;  p += (size_t)4096 * 1024 * 2;
  bf16* w2b  = (bf16*)p;  p += (size_t)1024 * 4096 * 2;
  bf16* o_bf = big + (size_t)ROWS * 3072;   // lives in big's tail during attention
  bf16* g_bf = big;                          // reuses big after attention done

  cast_kernel<<<3072 * 1024 / 8 / 256, 256, 0, stream>>>(w_qkv, wqb, 3072 * 1024);
  cast_kernel<<<1024 * 1024 / 8 / 256, 256, 0, stream>>>(w_out, wob, 1024 * 1024);
  cast_kernel<<<4096 * 1024 / 8 / 256, 256, 0, stream>>>(w1, w1b, 4096 * 1024);
  cast_kernel<<<1024 * 4096 / 8 / 256, 256, 0, stream>>>(w2, w2b, 1024 * 4096);

  pe_add_kernel<<<ROWS * 512 / 256, 256, 0, stream>>>(ff, idx, x_bf);
  gemm_bt<false, false><<<dim3(3072 / 128, ROWS / 128), 256, 0, stream>>>(
      x_bf, wqb, b_qkv, nullptr, big, ROWS, 3072, 1024);
  attn_kernel<<<(ROWS / 16) * 8, 256, 0, stream>>>(big, o_bf);
  gemm_bt<false, true><<<dim3(1024 / 128, ROWS / 128), 256, 0, stream>>>(
      o_bf, wob, b_out, x_bf, s_bf, ROWS, 1024, 1024);
  ln_kernel<bf16><<<ROWS, 256, 0, stream>>>(s_bf, g1, be1, h_bf);
  gemm_bt<true, false><<<dim3(4096 / 128, ROWS / 128), 256, 0, stream>>>(
      h_bf, w1b, b1, nullptr, g_bf, ROWS, 4096, 1024);
  gemm_bt<false, true><<<dim3(1024 / 128, ROWS / 128), 256, 0, stream>>>(
      g_bf, w2b, b2, h_bf, s_bf, ROWS, 1024, 4096);
  ln_kernel<float><<<ROWS, 256, 0, stream>>>(s_bf, g2, be2, out);
}

// Round 4
// 747.060 us; speedup vs baseline: 1.1013x; 1.0115x over previous
//
#include <hip/hip_runtime.h>
#include <math.h>

typedef __bf16 bf16;
typedef __bf16 bf16x8 __attribute__((ext_vector_type(8)));
typedef __bf16 bf16x4 __attribute__((ext_vector_type(4)));
typedef __bf16 bf16x2 __attribute__((ext_vector_type(2)));
typedef float f32x4 __attribute__((ext_vector_type(4)));

#define ROWS 16384   // B*T
#define DD   1024

// ---- direct global->LDS 16B DMA (gfx950). LDS dest = wave-uniform base + lane*16.
typedef __attribute__((address_space(3))) void* lds_vp;
typedef const __attribute__((address_space(1))) void* glb_vp;
__device__ __forceinline__ void gload16(const void* g, void* l) {
  __builtin_amdgcn_global_load_lds((glb_vp)g, (lds_vp)l, 16, 0, 0);
}

// ---------------- 0. cast f32 -> bf16 (weights) ----------------
__global__ __launch_bounds__(256) void cast_kernel(
    const float* __restrict__ src, bf16* __restrict__ dst, int n)
{
  int i = (blockIdx.x * 256 + threadIdx.x) * 8;
  if (i >= n) return;
  float4 a = *(const float4*)(src + i);
  float4 b = *(const float4*)(src + i + 4);
  bf16x8 o;
  o[0] = (bf16)a.x; o[1] = (bf16)a.y; o[2] = (bf16)a.z; o[3] = (bf16)a.w;
  o[4] = (bf16)b.x; o[5] = (bf16)b.y; o[6] = (bf16)b.z; o[7] = (bf16)b.w;
  *(bf16x8*)(dst + i) = o;
}

// ---------------- 1. x = frame_features + sinusoidal PE (f32 in, bf16 out) ----
__global__ __launch_bounds__(256) void pe_add_kernel(
    const float* __restrict__ ff, const int* __restrict__ idx, bf16* __restrict__ x)
{
  int p   = blockIdx.x * 256 + threadIdx.x;   // over ROWS*512 sin/cos pairs
  int row = p >> 9;
  int j   = p & 511;
  float pos = (float)idx[row];
  float d2  = (float)(2 * j) * (1.0f / 1024.0f);
  float dv  = expf(-9.210340371976184f * d2);   // 10000^(-2j/D)
  float ang = pos * dv;
  float s, c;
  sincosf(ang, &s, &c);
  int base = row * 1024 + 2 * j;
  float2 f = *(const float2*)(ff + base);
  bf16x2 o;
  o[0] = (bf16)(f.x + s);
  o[1] = (bf16)(f.y + c);
  *(bf16x2*)(x + base) = o;
}

// ---------------- 2. GEMM: C[M,N] = A[M,K] * Bw[N,K]^T + bias (+resid) (gelu?) ----
// m97 structure + XOR-swizzled LDS (kills 8-way frag-read conflicts) +
// LDS-repacked coalesced epilogue. XCD swizzle: lid&7 -> XCD owns M-stripe.
// Requires gridDim.x % 8 == 0 is NOT needed; requires total M blocks = 128.
template<bool GELU, bool RES>
__global__ __launch_bounds__(256, 2) void gemm_bt(
    const bf16* __restrict__ A, const bf16* __restrict__ Bw,
    const float* __restrict__ bias, const bf16* __restrict__ resid,
    bf16* __restrict__ C, int M, int N, int K)
{
  __shared__ bf16 smem[8192];   // 16 KB: sA|sB in K-loop, repack buf in epilogue
  bf16* sA = smem;
  bf16* sB = smem + 4096;

  const int tid = threadIdx.x;

  int lid = blockIdx.y * gridDim.x + blockIdx.x;
  int xcd = lid & 7;
  int j   = lid >> 3;
  const int bm = (xcd * 16 + (j & 15)) * 128;
  const int bn = (j >> 4) * 128;

  const int wave = tid >> 6;
  const int lane = tid & 63;
  const int wr   = (wave >> 1) * 64;   // wave row offset in tile
  const int wc   = (wave & 1) * 64;    // wave col offset in tile
  const int ln   = lane & 15;
  const int q    = lane >> 4;

  // staging: chunk c in {wave, wave+4}; lane l -> row c*16 + (l>>2),
  // XOR-swizzled k-granule (l&3)^((l>>3)&3). LDS dest = chunk base + l*16B.
  const int srow = lane >> 2;
  const int sgr  = (((lane & 3) ^ ((lane >> 3) & 3))) * 8;

  // frag-read slot: global granule q lives in LDS slot q ^ ((row>>1)&3);
  // row = wr|wc + t*16 + ln, and (wr|wc)>>1, t*8 are 0 mod 4 -> slot uses ln only.
  const int slot = (q ^ ((ln >> 1) & 3)) * 8;

  f32x4 acc[4][4];
#pragma unroll
  for (int i = 0; i < 4; i++)
#pragma unroll
    for (int jj = 0; jj < 4; jj++) acc[i][jj] = {0.f, 0.f, 0.f, 0.f};

  const bf16* ga0 = A  + (size_t)(bm + wave * 16 + srow) * K + sgr;
  const bf16* ga1 = A  + (size_t)(bm + (wave + 4) * 16 + srow) * K + sgr;
  const bf16* gb0 = Bw + (size_t)(bn + wave * 16 + srow) * K + sgr;
  const bf16* gb1 = Bw + (size_t)(bn + (wave + 4) * 16 + srow) * K + sgr;
  bf16* la0 = &sA[(wave * 16) * 32];
  bf16* la1 = &sA[((wave + 4) * 16) * 32];
  bf16* lb0 = &sB[(wave * 16) * 32];
  bf16* lb1 = &sB[((wave + 4) * 16) * 32];

  for (int k0 = 0; k0 < K; k0 += 32) {
    __syncthreads();   // previous iter's LDS reads done
    gload16(ga0 + k0, la0);
    gload16(ga1 + k0, la1);
    gload16(gb0 + k0, lb0);
    gload16(gb1 + k0, lb1);
    __syncthreads();   // compiler inserts s_waitcnt vmcnt(0) before barrier

    bf16x8 af[4], bfr[4];
#pragma unroll
    for (int t = 0; t < 4; t++) {
      af[t]  = *(const bf16x8*)(&sA[(wr + t * 16 + ln) * 32 + slot]);
      bfr[t] = *(const bf16x8*)(&sB[(wc + t * 16 + ln) * 32 + slot]);
    }
#pragma unroll
    for (int tm = 0; tm < 4; tm++)
#pragma unroll
      for (int tn = 0; tn < 4; tn++)
        acc[tm][tn] = __builtin_amdgcn_mfma_f32_16x16x32_bf16(
            af[tm], bfr[tn], acc[tm][tn], 0, 0, 0);
  }

  // ---- epilogue: 4 passes (one per tm). C/D layout col=lane&15, row=q*4+reg.
  // Write acc+bias (bf16) into LDS 32x128 (stride 132: 2-way banks), read back
  // row-major, apply resid/GELU wide, store 2x16B per thread (full lines).
  const int lr_w = (wave >> 1) * 16 + q * 4;       // LDS row base for writes
  const int lr_r = tid >> 3;                       // LDS row for reads (0..31)
  const int cb   = (tid & 7) * 16;                 // col base for reads
#pragma unroll
  for (int tm = 0; tm < 4; tm++) {
    __syncthreads();   // prior pass reads / K-loop LDS reads done
#pragma unroll
    for (int tn = 0; tn < 4; tn++) {
      int gn = bn + wc + tn * 16 + ln;
      float bv = bias[gn];
#pragma unroll
      for (int i = 0; i < 4; i++)
        smem[(lr_w + i) * 132 + wc + tn * 16 + ln] = (bf16)(acc[tm][tn][i] + bv);
    }
    __syncthreads();
    int gR = bm + (lr_r >> 4) * 64 + tm * 16 + (lr_r & 15);
    size_t rowoff = (size_t)gR * N + bn + cb;
    bf16x8 v0 = *(const bf16x8*)&smem[lr_r * 132 + cb];
    bf16x8 v1 = *(const bf16x8*)&smem[lr_r * 132 + cb + 8];
    if (RES) {
      bf16x8 r0 = *(const bf16x8*)(resid + rowoff);
      bf16x8 r1 = *(const bf16x8*)(resid + rowoff + 8);
#pragma unroll
      for (int u = 0; u < 8; u++) {
        v0[u] = (bf16)((float)v0[u] + (float)r0[u]);
        v1[u] = (bf16)((float)v1[u] + (float)r1[u]);
      }
    }
    if (GELU) {
#pragma unroll
      for (int u = 0; u < 8; u++) {
        float a = (float)v0[u], b = (float)v1[u];
        v0[u] = (bf16)(0.5f * a * (1.0f + erff(a * 0.70710678118654752f)));
        v1[u] = (bf16)(0.5f * b * (1.0f + erff(b * 0.70710678118654752f)));
      }
    }
    *(bf16x8*)(C + rowoff)     = v0;
    *(bf16x8*)(C + rowoff + 8) = v1;
  }
}

// ---------------- 3. windowed attention: one block per (window, head) ----------
__global__ __launch_bounds__(256) void attn_kernel(
    const bf16* __restrict__ qkv, bf16* __restrict__ o)
{
  __shared__ float sq[16][132], sk[16][132], sv[16][132];
  __shared__ float ss[16][17];

  int wid = blockIdx.x;
  int h   = wid & 7;
  int win = wid >> 3;
  int tb  = win * 16;     // token base row

  int t  = threadIdx.x;
  int r  = t >> 4;        // 0..15
  int c8 = (t & 15) * 8;  // 0..120

  const bf16* base = qkv + (size_t)(tb + r) * 3072 + c8;
  bf16x8 qv = *(const bf16x8*)(base + h * 128);
  bf16x8 kv = *(const bf16x8*)(base + 1024 + h * 128);
  bf16x8 vv = *(const bf16x8*)(base + 2048 + h * 128);
#pragma unroll
  for (int u = 0; u < 8; u++) {
    sq[r][c8 + u] = (float)qv[u];
    sk[r][c8 + u] = (float)kv[u];
    sv[r][c8 + u] = (float)vv[u];
  }
  __syncthreads();

  {  // scores: thread (i,j) does 128-dot
    int i = t >> 4, jj = t & 15;
    float s = 0.f;
#pragma unroll 8
    for (int d = 0; d < 128; d++) s += sq[i][d] * sk[jj][d];
    ss[i][jj] = s * 0.08838834764831845f;   // 1/sqrt(128)
  }
  __syncthreads();

  if (t < 16) {  // softmax, one thread per row
    float m = -1e30f;
    for (int jj = 0; jj < 16; jj++) m = fmaxf(m, ss[t][jj]);
    float sum = 0.f;
    for (int jj = 0; jj < 16; jj++) { float e = expf(ss[t][jj] - m); ss[t][jj] = e; sum += e; }
    float inv = 1.0f / sum;
    for (int jj = 0; jj < 16; jj++) ss[t][jj] *= inv;
  }
  __syncthreads();

  {  // o = attn @ v : thread does 8 output elems
    int i = t >> 4; int d0 = (t & 15) * 8;
    float acc[8] = {0, 0, 0, 0, 0, 0, 0, 0};
#pragma unroll
    for (int jj = 0; jj < 16; jj++) {
      float a = ss[i][jj];
#pragma unroll
      for (int u = 0; u < 8; u++) acc[u] += a * sv[jj][d0 + u];
    }
    bf16* op = o + (size_t)(tb + i) * 1024 + h * 128 + d0;
#pragma unroll
    for (int u = 0; u < 8; u++) op[u] = (bf16)acc[u];
  }
}

// ---------------- 4. LayerNorm (row = 1024, biased var), templated output ------
template<typename OUT_T>
__global__ __launch_bounds__(256) void ln_kernel(
    const bf16* __restrict__ x, const float* __restrict__ g,
    const float* __restrict__ b, OUT_T* __restrict__ y)
{
  __shared__ float red[8];
  int row = blockIdx.x;
  int t   = threadIdx.x;
  int lane = t & 63, wave = t >> 6;

  bf16x4 v4 = *(const bf16x4*)(x + (size_t)row * 1024 + t * 4);
  float v[4];
  float s = 0.f, sq = 0.f;
#pragma unroll
  for (int u = 0; u < 4; u++) {
    v[u] = (float)v4[u];
    s += v[u];
    sq += v[u] * v[u];
  }
  for (int off = 32; off > 0; off >>= 1) {
    s  += __shfl_down(s, off);
    sq += __shfl_down(sq, off);
  }
  if (lane == 0) { red[wave * 2] = s; red[wave * 2 + 1] = sq; }
  __syncthreads();
  float st = red[0] + red[2] + red[4] + red[6];
  float qt = red[1] + red[3] + red[5] + red[7];
  float mean = st * (1.0f / 1024.0f);
  float var  = qt * (1.0f / 1024.0f) - mean * mean;
  float inv  = rsqrtf(var + 1e-5f);
  int c = t * 4;
  OUT_T* yr = y + (size_t)row * 1024 + c;
#pragma unroll
  for (int u = 0; u < 4; u++)
    yr[u] = (OUT_T)((v[u] - mean) * inv * g[c + u] + b[c + u]);
}

// ---------------- launch ----------------
extern "C" void kernel_launch(void* const* d_in, const int* in_sizes, int n_in,
                              void* d_out, int out_size, void* d_ws, size_t ws_size,
                              hipStream_t stream) {
  const float* ff    = (const float*)d_in[0];
  const int*   idx   = (const int*)d_in[1];
  const float* w_qkv = (const float*)d_in[2];
  const float* b_qkv = (const float*)d_in[3];
  const float* w_out = (const float*)d_in[4];
  const float* b_out = (const float*)d_in[5];
  const float* w1    = (const float*)d_in[6];
  const float* b1    = (const float*)d_in[7];
  const float* w2    = (const float*)d_in[8];
  const float* b2    = (const float*)d_in[9];
  const float* g1    = (const float*)d_in[10];
  const float* be1   = (const float*)d_in[11];
  const float* g2    = (const float*)d_in[12];
  const float* be2   = (const float*)d_in[13];
  float* out = (float*)d_out;

  char* p = (char*)d_ws;
  bf16* x_bf = (bf16*)p;  p += (size_t)ROWS * 1024 * 2;   // 32MB
  bf16* big  = (bf16*)p;  p += (size_t)ROWS * 4096 * 2;   // 128MB: qkv|o, later gelu acts
  bf16* s_bf = (bf16*)p;  p += (size_t)ROWS * 1024 * 2;   // 32MB
  bf16* h_bf = (bf16*)p;  p += (size_t)ROWS * 1024 * 2;   // 32MB
  bf16* wqb  = (bf16*)p;  p += (size_t)3072 * 1024 * 2;
  bf16* wob  = (bf16*)p;  p += (size_t)1024 * 1024 * 2;
  bf16* w1b  = (bf16*)p;  p += (size_t)4096 * 1024 * 2;
  bf16* w2b  = (bf16*)p;  p += (size_t)1024 * 4096 * 2;
  bf16* o_bf = big + (size_t)ROWS * 3072;   // lives in big's tail during attention
  bf16* g_bf = big;                          // reuses big after attention done

  cast_kernel<<<3072 * 1024 / 8 / 256, 256, 0, stream>>>(w_qkv, wqb, 3072 * 1024);
  cast_kernel<<<1024 * 1024 / 8 / 256, 256, 0, stream>>>(w_out, wob, 1024 * 1024);
  cast_kernel<<<4096 * 1024 / 8 / 256, 256, 0, stream>>>(w1, w1b, 4096 * 1024);
  cast_kernel<<<1024 * 4096 / 8 / 256, 256, 0, stream>>>(w2, w2b, 1024 * 4096);

  pe_add_kernel<<<ROWS * 512 / 256, 256, 0, stream>>>(ff, idx, x_bf);
  gemm_bt<false, false><<<dim3(3072 / 128, ROWS / 128), 256, 0, stream>>>(
      x_bf, wqb, b_qkv, nullptr, big, ROWS, 3072, 1024);
  attn_kernel<<<(ROWS / 16) * 8, 256, 0, stream>>>(big, o_bf);
  gemm_bt<false, true><<<dim3(1024 / 128, ROWS / 128), 256, 0, stream>>>(
      o_bf, wob, b_out, x_bf, s_bf, ROWS, 1024, 1024);
  ln_kernel<bf16><<<ROWS, 256, 0, stream>>>(s_bf, g1, be1, h_bf);
  gemm_bt<true, false><<<dim3(4096 / 128, ROWS / 128), 256, 0, stream>>>(
      h_bf, w1b, b1, nullptr, g_bf, ROWS, 4096, 1024);
  gemm_bt<false, true><<<dim3(1024 / 128, ROWS / 128), 256, 0, stream>>>(
      g_bf, w2b, b2, h_bf, s_bf, ROWS, 1024, 4096);
  ln_kernel<float><<<ROWS, 256, 0, stream>>>(s_bf, g2, be2, out);
}